// Round 1
// baseline (72.375 us; speedup 1.0000x reference)
//
#include <hip/hip_runtime.h>
#include <hip/hip_bf16.h>

#define POOL 7
#define HW 128
#define CH 1024
#define NROI 512

// One block per (roi, py, px). 256 threads, each handles one float4 of channels.
__global__ __launch_bounds__(256) void roi_align_kernel(
    const float* __restrict__ img,   // [128][128][1024]
    const int*   __restrict__ rois,  // [512][4] = x,y,w,h
    float*       __restrict__ out)   // [512][7][7][1024]
{
    const int bid = blockIdx.x;             // r*49 + py*7 + px
    const int r  = bid / 49;
    const int pp = bid - r * 49;
    const int py = pp / 7;
    const int px = pp - py * 7;

    // ROI (block-uniform)
    const int4 roi = ((const int4*)rois)[r];
    const int rx = roi.x, ry = roi.y, rw = roi.z, rh = roi.w;

    // y axis sample
    const float hf = (float)rh;
    float cy = ((float)py + 0.5f) * (hf / (float)POOL) - 0.5f;
    cy = fminf(fmaxf(cy, 0.0f), fmaxf(hf - 1.0f, 0.0f));
    const int  iy0 = (int)floorf(cy);
    const int  iy1 = min(iy0 + 1, rh - 1);
    const float ty = cy - (float)iy0;

    // x axis sample
    const float wf = (float)rw;
    float cx = ((float)px + 0.5f) * (wf / (float)POOL) - 0.5f;
    cx = fminf(fmaxf(cx, 0.0f), fmaxf(wf - 1.0f, 0.0f));
    const int  ix0 = (int)floorf(cx);
    const int  ix1 = min(ix0 + 1, rw - 1);
    const float tx = cx - (float)ix0;

    const int y0 = ry + iy0, y1 = ry + iy1;
    const int x0 = rx + ix0, x1 = rx + ix1;

    const float4* p00 = (const float4*)(img + (size_t)(y0 * HW + x0) * CH);
    const float4* p01 = (const float4*)(img + (size_t)(y0 * HW + x1) * CH);
    const float4* p10 = (const float4*)(img + (size_t)(y1 * HW + x0) * CH);
    const float4* p11 = (const float4*)(img + (size_t)(y1 * HW + x1) * CH);

    const int c = threadIdx.x;  // float4 index, 0..255

    const float4 v00 = p00[c];
    const float4 v01 = p01[c];
    const float4 v10 = p10[c];
    const float4 v11 = p11[c];

    float4 res;
    {
        float top = v00.x + tx * (v01.x - v00.x);
        float bot = v10.x + tx * (v11.x - v10.x);
        res.x = top + ty * (bot - top);
    }
    {
        float top = v00.y + tx * (v01.y - v00.y);
        float bot = v10.y + tx * (v11.y - v10.y);
        res.y = top + ty * (bot - top);
    }
    {
        float top = v00.z + tx * (v01.z - v00.z);
        float bot = v10.z + tx * (v11.z - v10.z);
        res.z = top + ty * (bot - top);
    }
    {
        float top = v00.w + tx * (v01.w - v00.w);
        float bot = v10.w + tx * (v11.w - v10.w);
        res.w = top + ty * (bot - top);
    }

    ((float4*)out)[(size_t)bid * 256 + c] = res;
}

extern "C" void kernel_launch(void* const* d_in, const int* in_sizes, int n_in,
                              void* d_out, int out_size, void* d_ws, size_t ws_size,
                              hipStream_t stream) {
    const float* img  = (const float*)d_in[0];
    const int*   rois = (const int*)d_in[1];
    float*       out  = (float*)d_out;

    const int nblocks = NROI * POOL * POOL;  // 25088
    roi_align_kernel<<<nblocks, 256, 0, stream>>>(img, rois, out);
}

// Round 2
// 71.215 us; speedup vs baseline: 1.0163x; 1.0163x over previous
//
#include <hip/hip_runtime.h>
#include <hip/hip_bf16.h>

#define POOL 7
#define HW 128
#define CH 1024
#define NROI 512
#define NB (NROI * POOL * POOL)   // 25088
#define NXCD 8
#define NB_PER_XCD (NB / NXCD)    // 3136

// ---------------------------------------------------------------------------
// Kernel 1: sort ROI indices by (y, x) so dispatch order has spatial locality.
// 512 elements, single block bitonic sort in LDS. Key = y<<23 | x<<14 | idx
// (keys unique -> deterministic).
// ---------------------------------------------------------------------------
__global__ __launch_bounds__(NROI) void sort_rois_kernel(
    const int* __restrict__ rois,  // [512][4] x,y,w,h
    int*       __restrict__ perm)  // [512]
{
    __shared__ unsigned int keys[NROI];
    const int t = threadIdx.x;
    const int4 roi = ((const int4*)rois)[t];
    keys[t] = ((unsigned)roi.y << 23) | ((unsigned)roi.x << 14) | (unsigned)t;
    __syncthreads();

    for (int k = 2; k <= NROI; k <<= 1) {
        for (int j = k >> 1; j > 0; j >>= 1) {
            const int ixj = t ^ j;
            if (ixj > t) {
                const unsigned a = keys[t];
                const unsigned b = keys[ixj];
                const bool ascending = ((t & k) == 0);
                if ((a > b) == ascending) {  // keys unique, never equal
                    keys[t] = b;
                    keys[ixj] = a;
                }
            }
            __syncthreads();
        }
    }
    perm[t] = (int)(keys[t] & 0x3FFFu);
}

// ---------------------------------------------------------------------------
// Kernel 2: one block per (sorted-roi-slot, py, px); 256 threads, one float4
// of channels each. XCD-chunked swizzle: assume hw XCD = blockIdx % 8; give
// each XCD a contiguous run of sorted-ROI work for L2 locality.
// ---------------------------------------------------------------------------
__global__ __launch_bounds__(256) void roi_align_kernel(
    const float* __restrict__ img,   // [128][128][1024]
    const int*   __restrict__ rois,  // [512][4] = x,y,w,h
    const int*   __restrict__ perm,  // [512] sorted order
    float*       __restrict__ out)   // [512][7][7][1024]
{
    // logical index: contiguous chunk per XCD
    const int xcd = blockIdx.x & (NXCD - 1);
    const int l   = xcd * NB_PER_XCD + (blockIdx.x >> 3);

    const int slot = l / 49;
    const int pp   = l - slot * 49;
    const int py   = pp / 7;
    const int px   = pp - py * 7;
    const int r    = perm[slot];

    const int4 roi = ((const int4*)rois)[r];
    const int rx = roi.x, ry = roi.y, rw = roi.z, rh = roi.w;

    // y axis sample
    const float hf = (float)rh;
    float cy = ((float)py + 0.5f) * (hf / (float)POOL) - 0.5f;
    cy = fminf(fmaxf(cy, 0.0f), fmaxf(hf - 1.0f, 0.0f));
    const int  iy0 = (int)floorf(cy);
    const int  iy1 = min(iy0 + 1, rh - 1);
    const float ty = cy - (float)iy0;

    // x axis sample
    const float wf = (float)rw;
    float cx = ((float)px + 0.5f) * (wf / (float)POOL) - 0.5f;
    cx = fminf(fmaxf(cx, 0.0f), fmaxf(wf - 1.0f, 0.0f));
    const int  ix0 = (int)floorf(cx);
    const int  ix1 = min(ix0 + 1, rw - 1);
    const float tx = cx - (float)ix0;

    const int y0 = ry + iy0, y1 = ry + iy1;
    const int x0 = rx + ix0, x1 = rx + ix1;

    const float4* p00 = (const float4*)(img + (size_t)(y0 * HW + x0) * CH);
    const float4* p01 = (const float4*)(img + (size_t)(y0 * HW + x1) * CH);
    const float4* p10 = (const float4*)(img + (size_t)(y1 * HW + x0) * CH);
    const float4* p11 = (const float4*)(img + (size_t)(y1 * HW + x1) * CH);

    const int c = threadIdx.x;  // float4 index, 0..255

    const float4 v00 = p00[c];
    const float4 v01 = p01[c];
    const float4 v10 = p10[c];
    const float4 v11 = p11[c];

    float4 res;
    {
        float top = v00.x + tx * (v01.x - v00.x);
        float bot = v10.x + tx * (v11.x - v10.x);
        res.x = top + ty * (bot - top);
    }
    {
        float top = v00.y + tx * (v01.y - v00.y);
        float bot = v10.y + tx * (v11.y - v10.y);
        res.y = top + ty * (bot - top);
    }
    {
        float top = v00.z + tx * (v01.z - v00.z);
        float bot = v10.z + tx * (v11.z - v10.z);
        res.z = top + ty * (bot - top);
    }
    {
        float top = v00.w + tx * (v01.w - v00.w);
        float bot = v10.w + tx * (v11.w - v10.w);
        res.w = top + ty * (bot - top);
    }

    // output goes to the ORIGINAL roi index r
    const size_t obid = (size_t)r * 49 + pp;
    ((float4*)out)[obid * 256 + c] = res;
}

extern "C" void kernel_launch(void* const* d_in, const int* in_sizes, int n_in,
                              void* d_out, int out_size, void* d_ws, size_t ws_size,
                              hipStream_t stream) {
    const float* img  = (const float*)d_in[0];
    const int*   rois = (const int*)d_in[1];
    float*       out  = (float*)d_out;
    int*         perm = (int*)d_ws;  // 512 ints

    sort_rois_kernel<<<1, NROI, 0, stream>>>(rois, perm);
    roi_align_kernel<<<NB, 256, 0, stream>>>(img, rois, perm, out);
}

// Round 4
// 70.160 us; speedup vs baseline: 1.0316x; 1.0150x over previous
//
#include <hip/hip_runtime.h>
#include <hip/hip_bf16.h>

#define POOL 7
#define HW 128
#define CH 1024
#define NROI 512
#define NBLK (NROI * POOL)        // 3584 blocks: one per (roi, py)
#define NXCD 8
#define NB_PER_XCD (NBLK / NXCD)  // 448

typedef float f4 __attribute__((ext_vector_type(4)));  // native vector: works with nontemporal builtins

// ---------------------------------------------------------------------------
// Kernel 1: sort ROI indices by (y, x) for dispatch-order spatial locality.
// ---------------------------------------------------------------------------
__global__ __launch_bounds__(NROI) void sort_rois_kernel(
    const int* __restrict__ rois,  // [512][4] x,y,w,h
    int*       __restrict__ perm)  // [512]
{
    __shared__ unsigned int keys[NROI];
    const int t = threadIdx.x;
    const int4 roi = ((const int4*)rois)[t];
    keys[t] = ((unsigned)roi.y << 23) | ((unsigned)roi.x << 14) | (unsigned)t;
    __syncthreads();

    for (int k = 2; k <= NROI; k <<= 1) {
        for (int j = k >> 1; j > 0; j >>= 1) {
            const int ixj = t ^ j;
            if (ixj > t) {
                const unsigned a = keys[t];
                const unsigned b = keys[ixj];
                const bool ascending = ((t & k) == 0);
                if ((a > b) == ascending) {
                    keys[t] = b;
                    keys[ixj] = a;
                }
            }
            __syncthreads();
        }
    }
    perm[t] = (int)(keys[t] & 0x3FFFu);
}

// ---------------------------------------------------------------------------
// Kernel 2: one block per (sorted-roi-slot, py). 256 threads, one float4 of
// channels each, looping over the 7 px samples of the pooling row.
// All 28 loads issued per thread -> high MLP. Nontemporal stores keep the
// 100 MB output stream out of L2.
// ---------------------------------------------------------------------------
__global__ __launch_bounds__(256) void roi_align_kernel(
    const float* __restrict__ img,   // [128][128][1024]
    const int*   __restrict__ rois,  // [512][4] = x,y,w,h
    const int*   __restrict__ perm,  // [512] sorted order
    float*       __restrict__ out)   // [512][7][7][1024]
{
    // XCD-chunked swizzle: hw xcd = blockIdx % 8 -> contiguous sorted run each
    const int xcd = blockIdx.x & (NXCD - 1);
    const int l   = xcd * NB_PER_XCD + (blockIdx.x >> 3);

    const int slot = l / POOL;
    const int py   = l - slot * POOL;
    const int r    = perm[slot];

    const int4 roi = ((const int4*)rois)[r];
    const int rx = roi.x, ry = roi.y, rw = roi.z, rh = roi.w;

    // y axis sample (once per block)
    const float hf = (float)rh;
    float cy = ((float)py + 0.5f) * (hf / (float)POOL) - 0.5f;
    cy = fminf(fmaxf(cy, 0.0f), fmaxf(hf - 1.0f, 0.0f));
    const int  iy0 = (int)floorf(cy);
    const int  iy1 = min(iy0 + 1, rh - 1);
    const float ty = cy - (float)iy0;

    const int y0 = ry + iy0, y1 = ry + iy1;
    const float* row0 = img + (size_t)y0 * HW * CH;
    const float* row1 = img + (size_t)y1 * HW * CH;

    const int c = threadIdx.x;  // float4 index within channels
    const float wf = (float)rw;
    const float xscale = wf / (float)POOL;

    // Per-px x coordinates (unrolled, registers)
    int   x0a[POOL], x1a[POOL];
    float txa[POOL];
#pragma unroll
    for (int px = 0; px < POOL; ++px) {
        float cx = ((float)px + 0.5f) * xscale - 0.5f;
        cx = fminf(fmaxf(cx, 0.0f), fmaxf(wf - 1.0f, 0.0f));
        const int ix0 = (int)floorf(cx);
        const int ix1 = min(ix0 + 1, rw - 1);
        txa[px] = cx - (float)ix0;
        x0a[px] = rx + ix0;
        x1a[px] = rx + ix1;
    }

    // Issue all 28 loads (4 per px) for maximum MLP
    f4 v00[POOL], v01[POOL], v10[POOL], v11[POOL];
#pragma unroll
    for (int px = 0; px < POOL; ++px) {
        v00[px] = ((const f4*)(row0 + (size_t)x0a[px] * CH))[c];
        v01[px] = ((const f4*)(row0 + (size_t)x1a[px] * CH))[c];
        v10[px] = ((const f4*)(row1 + (size_t)x0a[px] * CH))[c];
        v11[px] = ((const f4*)(row1 + (size_t)x1a[px] * CH))[c];
    }

    // Blend + nontemporal store
    f4* orow = (f4*)out + ((size_t)r * 49 + (size_t)py * POOL) * 256 + c;
#pragma unroll
    for (int px = 0; px < POOL; ++px) {
        const float tx = txa[px];
        f4 top = v00[px] + tx * (v01[px] - v00[px]);
        f4 bot = v10[px] + tx * (v11[px] - v10[px]);
        f4 res = top + ty * (bot - top);
        __builtin_nontemporal_store(res, orow + (size_t)px * 256);
    }
}

extern "C" void kernel_launch(void* const* d_in, const int* in_sizes, int n_in,
                              void* d_out, int out_size, void* d_ws, size_t ws_size,
                              hipStream_t stream) {
    const float* img  = (const float*)d_in[0];
    const int*   rois = (const int*)d_in[1];
    float*       out  = (float*)d_out;
    int*         perm = (int*)d_ws;  // 512 ints

    sort_rois_kernel<<<1, NROI, 0, stream>>>(rois, perm);
    roi_align_kernel<<<NBLK, 256, 0, stream>>>(img, rois, perm, out);
}

// Round 5
// 69.223 us; speedup vs baseline: 1.0455x; 1.0135x over previous
//
#include <hip/hip_runtime.h>
#include <hip/hip_bf16.h>

#define POOL 7
#define HW 128
#define CH 1024
#define NROI 512
#define NBLK (NROI * POOL)        // 3584 blocks: one per (roi, py)
#define NXCD 8
#define NB_PER_XCD (NBLK / NXCD)  // 448

typedef float f4 __attribute__((ext_vector_type(4)));

// ---------------------------------------------------------------------------
// Kernel 1: counting sort of ROI indices by y (64 bins). 3 barriers total.
// Within-bin order is nondeterministic but only affects schedule, not output.
// ---------------------------------------------------------------------------
__global__ __launch_bounds__(NROI) void sort_rois_kernel(
    const int* __restrict__ rois,  // [512][4] x,y,w,h
    int*       __restrict__ perm)  // [512]
{
    __shared__ int hist[64];
    __shared__ int base[64];
    const int t = threadIdx.x;
    if (t < 64) hist[t] = 0;
    __syncthreads();

    const int y = rois[t * 4 + 1] & 63;
    atomicAdd(&hist[y], 1);
    __syncthreads();

    // exclusive prefix over 64 bins by a single wave (wave 0, lanes 0..63)
    if (t < 64) {
        int v = hist[t];
        int s = v;
        // inclusive scan via shfl_up across the 64-lane wave
        for (int off = 1; off < 64; off <<= 1) {
            int n = __shfl_up(s, off, 64);
            if ((t & 63) >= off) s += n;
        }
        base[t] = s - v;  // exclusive
    }
    __syncthreads();

    const int pos = atomicAdd(&base[y], 1);
    perm[pos] = t;
}

// ---------------------------------------------------------------------------
// Kernel 2: one block per (sorted-roi-slot, py). 256 threads, one float4 of
// channels each, over the 7 px samples of the pooling row. All 28 loads are
// issued before any compute (sched_barrier fence) for real MLP.
// ---------------------------------------------------------------------------
__global__ __launch_bounds__(256, 3) void roi_align_kernel(
    const float* __restrict__ img,   // [128][128][1024]
    const int*   __restrict__ rois,  // [512][4] = x,y,w,h
    const int*   __restrict__ perm,  // [512] sorted order
    float*       __restrict__ out)   // [512][7][7][1024]
{
    const int xcd = blockIdx.x & (NXCD - 1);
    const int l   = xcd * NB_PER_XCD + (blockIdx.x >> 3);

    const int slot = l / POOL;
    const int py   = l - slot * POOL;
    const int r    = perm[slot];

    const int4 roi = ((const int4*)rois)[r];
    const int rx = roi.x, ry = roi.y, rw = roi.z, rh = roi.w;

    // y axis sample (block-uniform)
    const float hf = (float)rh;
    float cy = ((float)py + 0.5f) * (hf / (float)POOL) - 0.5f;
    cy = fminf(fmaxf(cy, 0.0f), fmaxf(hf - 1.0f, 0.0f));
    const int  iy0 = (int)floorf(cy);
    const int  iy1 = min(iy0 + 1, rh - 1);
    const float ty = cy - (float)iy0;

    const int y0 = ry + iy0, y1 = ry + iy1;
    const float* row0 = img + (size_t)y0 * HW * CH;
    const float* row1 = img + (size_t)y1 * HW * CH;

    const int c = threadIdx.x;
    const float wf = (float)rw;
    const float xscale = wf / (float)POOL;

    int   x0a[POOL], x1a[POOL];
    float txa[POOL];
#pragma unroll
    for (int px = 0; px < POOL; ++px) {
        float cx = ((float)px + 0.5f) * xscale - 0.5f;
        cx = fminf(fmaxf(cx, 0.0f), fmaxf(wf - 1.0f, 0.0f));
        const int ix0 = (int)floorf(cx);
        const int ix1 = min(ix0 + 1, rw - 1);
        txa[px] = cx - (float)ix0;
        x0a[px] = rx + ix0;
        x1a[px] = rx + ix1;
    }

    // ---- load cluster: 28 independent 16B loads ----
    f4 v00[POOL], v01[POOL], v10[POOL], v11[POOL];
#pragma unroll
    for (int px = 0; px < POOL; ++px) {
        v00[px] = ((const f4*)(row0 + (size_t)x0a[px] * CH))[c];
        v01[px] = ((const f4*)(row0 + (size_t)x1a[px] * CH))[c];
        v10[px] = ((const f4*)(row1 + (size_t)x0a[px] * CH))[c];
        v11[px] = ((const f4*)(row1 + (size_t)x1a[px] * CH))[c];
    }
    // Fence: nothing crosses — loads stay hoisted, compute stays below.
    __builtin_amdgcn_sched_barrier(0);

    // ---- compute + nontemporal store cluster ----
    f4* orow = (f4*)out + ((size_t)r * 49 + (size_t)py * POOL) * 256 + c;
#pragma unroll
    for (int px = 0; px < POOL; ++px) {
        const float tx = txa[px];
        f4 top = v00[px] + tx * (v01[px] - v00[px]);
        f4 bot = v10[px] + tx * (v11[px] - v10[px]);
        f4 res = top + ty * (bot - top);
        __builtin_nontemporal_store(res, orow + (size_t)px * 256);
    }
}

extern "C" void kernel_launch(void* const* d_in, const int* in_sizes, int n_in,
                              void* d_out, int out_size, void* d_ws, size_t ws_size,
                              hipStream_t stream) {
    const float* img  = (const float*)d_in[0];
    const int*   rois = (const int*)d_in[1];
    float*       out  = (float*)d_out;
    int*         perm = (int*)d_ws;  // 512 ints

    sort_rois_kernel<<<1, NROI, 0, stream>>>(rois, perm);
    roi_align_kernel<<<NBLK, 256, 0, stream>>>(img, rois, perm, out);
}

// Round 6
// 45.784 us; speedup vs baseline: 1.5808x; 1.5119x over previous
//
#include <hip/hip_runtime.h>
#include <hip/hip_bf16.h>

#define POOL 7
#define HW 128
#define CH 1024
#define NROI 512
#define NXCD 8
#define CPG 128                       // channels per group (8 groups)
#define NUNITS (NROI * POOL)          // 3584 (slot, py) units
#define NQUAD (NUNITS / 4)            // 896 quads of 4 units (one per wave)

typedef float f2 __attribute__((ext_vector_type(2)));

// ---------------------------------------------------------------------------
// Kernel 1: counting sort of ROI indices by y (64 bins). 3 barriers total.
// ---------------------------------------------------------------------------
__global__ __launch_bounds__(NROI) void sort_rois_kernel(
    const int* __restrict__ rois,  // [512][4] x,y,w,h
    int*       __restrict__ perm)  // [512]
{
    __shared__ int hist[64];
    __shared__ int base[64];
    const int t = threadIdx.x;
    if (t < 64) hist[t] = 0;
    __syncthreads();

    const int y = rois[t * 4 + 1] & 63;
    atomicAdd(&hist[y], 1);
    __syncthreads();

    if (t < 64) {
        int v = hist[t];
        int s = v;
        for (int off = 1; off < 64; off <<= 1) {
            int n = __shfl_up(s, off, 64);
            if ((t & 63) >= off) s += n;
        }
        base[t] = s - v;  // exclusive
    }
    __syncthreads();

    const int pos = atomicAdd(&base[y], 1);
    perm[pos] = t;
}

// ---------------------------------------------------------------------------
// Kernel 2: channel-group sliced. blockIdx = quad*8 + g, so hw XCD (= blockIdx
// % 8) is pinned to channel group g: each XCD's L2 only sees its own 8 MB
// channel slice; y-sorted ROI order makes the sliding window L2-resident.
// 256 threads = 4 independent waves; wave w handles unit quad*4+w = (slot,py),
// 128 channels via float2 per lane, looping 7 px with full preload.
// ---------------------------------------------------------------------------
__global__ __launch_bounds__(256) void roi_align_kernel(
    const float* __restrict__ img,   // [128][128][1024]
    const int*   __restrict__ rois,  // [512][4] = x,y,w,h
    const int*   __restrict__ perm,  // [512] sorted order
    float*       __restrict__ out)   // [512][7][7][1024]
{
    const int g    = blockIdx.x & (NXCD - 1);   // channel group == XCD
    const int quad = blockIdx.x >> 3;
    const int wave = threadIdx.x >> 6;
    const int lane = threadIdx.x & 63;

    const int unit = quad * 4 + wave;           // 0..3583
    const int slot = unit / POOL;
    const int py   = unit - slot * POOL;
    const int r    = perm[slot];

    const int4 roi = ((const int4*)rois)[r];
    const int rx = roi.x, ry = roi.y, rw = roi.z, rh = roi.w;

    // y axis sample (wave-uniform)
    const float hf = (float)rh;
    float cy = ((float)py + 0.5f) * (hf / (float)POOL) - 0.5f;
    cy = fminf(fmaxf(cy, 0.0f), fmaxf(hf - 1.0f, 0.0f));
    const int  iy0 = (int)floorf(cy);
    const int  iy1 = min(iy0 + 1, rh - 1);
    const float ty = cy - (float)iy0;

    const int y0 = ry + iy0, y1 = ry + iy1;
    // include the channel-group offset once
    const float* row0 = img + (size_t)y0 * HW * CH + g * CPG;
    const float* row1 = img + (size_t)y1 * HW * CH + g * CPG;

    const float wf = (float)rw;
    const float xscale = wf / (float)POOL;

    int   x0a[POOL], x1a[POOL];
    float txa[POOL];
#pragma unroll
    for (int px = 0; px < POOL; ++px) {
        float cx = ((float)px + 0.5f) * xscale - 0.5f;
        cx = fminf(fmaxf(cx, 0.0f), fmaxf(wf - 1.0f, 0.0f));
        const int ix0 = (int)floorf(cx);
        const int ix1 = min(ix0 + 1, rw - 1);
        txa[px] = cx - (float)ix0;
        x0a[px] = rx + ix0;
        x1a[px] = rx + ix1;
    }

    // ---- load cluster: 28 independent 8B loads ----
    f2 v00[POOL], v01[POOL], v10[POOL], v11[POOL];
#pragma unroll
    for (int px = 0; px < POOL; ++px) {
        v00[px] = ((const f2*)(row0 + (size_t)x0a[px] * CH))[lane];
        v01[px] = ((const f2*)(row0 + (size_t)x1a[px] * CH))[lane];
        v10[px] = ((const f2*)(row1 + (size_t)x0a[px] * CH))[lane];
        v11[px] = ((const f2*)(row1 + (size_t)x1a[px] * CH))[lane];
    }
    __builtin_amdgcn_sched_barrier(0);

    // ---- compute + nontemporal store ----
    float* obase = out + ((size_t)r * 49 + (size_t)py * POOL) * CH + g * CPG;
#pragma unroll
    for (int px = 0; px < POOL; ++px) {
        const float tx = txa[px];
        f2 top = v00[px] + tx * (v01[px] - v00[px]);
        f2 bot = v10[px] + tx * (v11[px] - v10[px]);
        f2 res = top + ty * (bot - top);
        __builtin_nontemporal_store(res, (f2*)(obase + (size_t)px * CH) + lane);
    }
}

extern "C" void kernel_launch(void* const* d_in, const int* in_sizes, int n_in,
                              void* d_out, int out_size, void* d_ws, size_t ws_size,
                              hipStream_t stream) {
    const float* img  = (const float*)d_in[0];
    const int*   rois = (const int*)d_in[1];
    float*       out  = (float*)d_out;
    int*         perm = (int*)d_ws;  // 512 ints

    sort_rois_kernel<<<1, NROI, 0, stream>>>(rois, perm);
    roi_align_kernel<<<NQUAD * NXCD, 256, 0, stream>>>(img, rois, perm, out);
}

// Round 7
// 44.995 us; speedup vs baseline: 1.6085x; 1.0175x over previous
//
#include <hip/hip_runtime.h>
#include <hip/hip_bf16.h>

#define POOL 7
#define HW 128
#define CH 1024
#define NROI 512
#define NXCD 8
#define CPG 128                       // channels per group (8 groups = 8 XCDs)
#define NUNITS (NROI * POOL)          // 3584 (slot, py) units
#define WPG 896                       // waves per channel-group; 896*4 = 3584 units
#define NBLK_P ((WPG / 4) * NXCD)     // 224 blocks/group * 8 = 1792 blocks (7/CU)

typedef float f2 __attribute__((ext_vector_type(2)));

// ---------------------------------------------------------------------------
// Kernel 1: counting sort of ROI indices by y (64 bins). 3 barriers total.
// ---------------------------------------------------------------------------
__global__ __launch_bounds__(NROI) void sort_rois_kernel(
    const int* __restrict__ rois,  // [512][4] x,y,w,h
    int*       __restrict__ perm)  // [512]
{
    __shared__ int hist[64];
    __shared__ int base[64];
    const int t = threadIdx.x;
    if (t < 64) hist[t] = 0;
    __syncthreads();

    const int y = rois[t * 4 + 1] & 63;
    atomicAdd(&hist[y], 1);
    __syncthreads();

    if (t < 64) {
        int v = hist[t];
        int s = v;
        for (int off = 1; off < 64; off <<= 1) {
            int n = __shfl_up(s, off, 64);
            if ((t & 63) >= off) s += n;
        }
        base[t] = s - v;  // exclusive
    }
    __syncthreads();

    const int pos = atomicAdd(&base[y], 1);
    perm[pos] = t;
}

// ---------------------------------------------------------------------------
// Kernel 2: persistent channel-sliced. blockIdx%8 = channel group g (pinned to
// the hw XCD), 4 waves/block, wave id wid in [0,896) per group. Each wave
// processes exactly 4 units u = wid + i*896 — balanced, co-resident the whole
// kernel, concurrent window per step = contiguous 896-unit y-sorted band.
// ---------------------------------------------------------------------------
__global__ __launch_bounds__(256) void roi_align_kernel(
    const float* __restrict__ img,   // [128][128][1024]
    const int*   __restrict__ rois,  // [512][4] = x,y,w,h
    const int*   __restrict__ perm,  // [512] sorted order
    float*       __restrict__ out)   // [512][7][7][1024]
{
    const int g    = blockIdx.x & (NXCD - 1);   // channel group == XCD
    const int wave = threadIdx.x >> 6;
    const int lane = threadIdx.x & 63;
    const int wid  = ((blockIdx.x >> 3) << 2) + wave;  // 0..895

    const float* gimg = img + g * CPG;
    float*       gout = out + g * CPG;

#pragma unroll 1
    for (int u = wid; u < NUNITS; u += WPG) {
        const int slot = u / POOL;
        const int py   = u - slot * POOL;
        const int r    = perm[slot];

        const int4 roi = ((const int4*)rois)[r];
        const int rx = roi.x, ry = roi.y, rw = roi.z, rh = roi.w;

        // y axis sample (wave-uniform)
        const float hf = (float)rh;
        float cy = ((float)py + 0.5f) * (hf / (float)POOL) - 0.5f;
        cy = fminf(fmaxf(cy, 0.0f), fmaxf(hf - 1.0f, 0.0f));
        const int  iy0 = (int)floorf(cy);
        const int  iy1 = min(iy0 + 1, rh - 1);
        const float ty = cy - (float)iy0;

        const int y0 = ry + iy0, y1 = ry + iy1;
        const float* row0 = gimg + (size_t)y0 * HW * CH;
        const float* row1 = gimg + (size_t)y1 * HW * CH;

        const float wf = (float)rw;
        const float xscale = wf / (float)POOL;

        int   x0a[POOL], x1a[POOL];
        float txa[POOL];
#pragma unroll
        for (int px = 0; px < POOL; ++px) {
            float cx = ((float)px + 0.5f) * xscale - 0.5f;
            cx = fminf(fmaxf(cx, 0.0f), fmaxf(wf - 1.0f, 0.0f));
            const int ix0 = (int)floorf(cx);
            const int ix1 = min(ix0 + 1, rw - 1);
            txa[px] = cx - (float)ix0;
            x0a[px] = rx + ix0;
            x1a[px] = rx + ix1;
        }

        // ---- load cluster: 28 independent 8B loads ----
        f2 v00[POOL], v01[POOL], v10[POOL], v11[POOL];
#pragma unroll
        for (int px = 0; px < POOL; ++px) {
            v00[px] = ((const f2*)(row0 + (size_t)x0a[px] * CH))[lane];
            v01[px] = ((const f2*)(row0 + (size_t)x1a[px] * CH))[lane];
            v10[px] = ((const f2*)(row1 + (size_t)x0a[px] * CH))[lane];
            v11[px] = ((const f2*)(row1 + (size_t)x1a[px] * CH))[lane];
        }
        __builtin_amdgcn_sched_barrier(0);

        // ---- compute + nontemporal store ----
        float* obase = gout + ((size_t)r * 49 + (size_t)py * POOL) * CH;
#pragma unroll
        for (int px = 0; px < POOL; ++px) {
            const float tx = txa[px];
            f2 top = v00[px] + tx * (v01[px] - v00[px]);
            f2 bot = v10[px] + tx * (v11[px] - v10[px]);
            f2 res = top + ty * (bot - top);
            __builtin_nontemporal_store(res, (f2*)(obase + (size_t)px * CH) + lane);
        }
    }
}

extern "C" void kernel_launch(void* const* d_in, const int* in_sizes, int n_in,
                              void* d_out, int out_size, void* d_ws, size_t ws_size,
                              hipStream_t stream) {
    const float* img  = (const float*)d_in[0];
    const int*   rois = (const int*)d_in[1];
    float*       out  = (float*)d_out;
    int*         perm = (int*)d_ws;  // 512 ints

    sort_rois_kernel<<<1, NROI, 0, stream>>>(rois, perm);
    roi_align_kernel<<<NBLK_P, 256, 0, stream>>>(img, rois, perm, out);
}

// Round 8
// 38.779 us; speedup vs baseline: 1.8663x; 1.1603x over previous
//
#include <hip/hip_runtime.h>
#include <hip/hip_bf16.h>

#define POOL 7
#define HW 128
#define CH 1024
#define NROI 512
#define NXCD 8
#define CPG 128                       // channels per group (8 groups = 8 XCDs)
#define NUNITS (NROI * POOL)          // 3584 (roi, py) units
#define WPG 896                       // waves per channel-group; 896*4 = 3584 units
#define NBLK_P ((WPG / 4) * NXCD)     // 224 blocks/group * 8 = 1792 blocks

typedef float f2 __attribute__((ext_vector_type(2)));

// ---------------------------------------------------------------------------
// Persistent channel-sliced ROI-align, identity processing order.
// blockIdx%8 = channel group g (pinned to hw XCD). Each wave processes 4
// units u = wid + i*896 in ascending r order, so every XCD's 512B-granule
// write stream walks the output monotonically (DRAM row locality), and its
// read slice (8.4 MB) stays L2/L3-resident.
// ---------------------------------------------------------------------------
__global__ __launch_bounds__(256) void roi_align_kernel(
    const float* __restrict__ img,   // [128][128][1024]
    const int*   __restrict__ rois,  // [512][4] = x,y,w,h
    float*       __restrict__ out)   // [512][7][7][1024]
{
    const int g    = blockIdx.x & (NXCD - 1);   // channel group == XCD
    const int wave = threadIdx.x >> 6;
    const int lane = threadIdx.x & 63;
    const int wid  = ((blockIdx.x >> 3) << 2) + wave;  // 0..895

    const float* gimg = img + g * CPG;
    float*       gout = out + g * CPG;

#pragma unroll 1
    for (int u = wid; u < NUNITS; u += WPG) {
        const int r  = u / POOL;
        const int py = u - r * POOL;

        const int4 roi = ((const int4*)rois)[r];
        const int rx = roi.x, ry = roi.y, rw = roi.z, rh = roi.w;

        // y axis sample (wave-uniform)
        const float hf = (float)rh;
        float cy = ((float)py + 0.5f) * (hf / (float)POOL) - 0.5f;
        cy = fminf(fmaxf(cy, 0.0f), fmaxf(hf - 1.0f, 0.0f));
        const int  iy0 = (int)floorf(cy);
        const int  iy1 = min(iy0 + 1, rh - 1);
        const float ty = cy - (float)iy0;

        const int y0 = ry + iy0, y1 = ry + iy1;
        const float* row0 = gimg + (size_t)y0 * HW * CH;
        const float* row1 = gimg + (size_t)y1 * HW * CH;

        const float wf = (float)rw;
        const float xscale = wf / (float)POOL;

        int   x0a[POOL], x1a[POOL];
        float txa[POOL];
#pragma unroll
        for (int px = 0; px < POOL; ++px) {
            float cx = ((float)px + 0.5f) * xscale - 0.5f;
            cx = fminf(fmaxf(cx, 0.0f), fmaxf(wf - 1.0f, 0.0f));
            const int ix0 = (int)floorf(cx);
            const int ix1 = min(ix0 + 1, rw - 1);
            txa[px] = cx - (float)ix0;
            x0a[px] = rx + ix0;
            x1a[px] = rx + ix1;
        }

        // ---- load cluster: 28 independent 8B loads ----
        f2 v00[POOL], v01[POOL], v10[POOL], v11[POOL];
#pragma unroll
        for (int px = 0; px < POOL; ++px) {
            v00[px] = ((const f2*)(row0 + (size_t)x0a[px] * CH))[lane];
            v01[px] = ((const f2*)(row0 + (size_t)x1a[px] * CH))[lane];
            v10[px] = ((const f2*)(row1 + (size_t)x0a[px] * CH))[lane];
            v11[px] = ((const f2*)(row1 + (size_t)x1a[px] * CH))[lane];
        }
        __builtin_amdgcn_sched_barrier(0);

        // ---- compute + nontemporal store (ascending addresses) ----
        float* obase = gout + ((size_t)r * 49 + (size_t)py * POOL) * CH;
#pragma unroll
        for (int px = 0; px < POOL; ++px) {
            const float tx = txa[px];
            f2 top = v00[px] + tx * (v01[px] - v00[px]);
            f2 bot = v10[px] + tx * (v11[px] - v10[px]);
            f2 res = top + ty * (bot - top);
            __builtin_nontemporal_store(res, (f2*)(obase + (size_t)px * CH) + lane);
        }
    }
}

extern "C" void kernel_launch(void* const* d_in, const int* in_sizes, int n_in,
                              void* d_out, int out_size, void* d_ws, size_t ws_size,
                              hipStream_t stream) {
    const float* img  = (const float*)d_in[0];
    const int*   rois = (const int*)d_in[1];
    float*       out  = (float*)d_out;

    roi_align_kernel<<<NBLK_P, 256, 0, stream>>>(img, rois, out);
}

// Round 9
// 36.460 us; speedup vs baseline: 1.9850x; 1.0636x over previous
//
#include <hip/hip_runtime.h>
#include <hip/hip_bf16.h>

#define POOL 7
#define HW 128
#define CH 1024
#define NROI 512
#define NXCD 8
#define CPG 128                       // channels per group (8 groups = 8 XCDs)
#define NUNITS (NROI * POOL)          // 3584 (roi, py) units
#define NPAIR (NUNITS / 2)            // 1792 pairs; each wave handles 2 pairs
#define WPG 896                       // waves per channel-group
#define NBLK_P ((WPG / 4) * NXCD)     // 224 blocks/group * 8 = 1792 blocks

typedef float f4 __attribute__((ext_vector_type(4)));

// ---------------------------------------------------------------------------
// Persistent channel-sliced ROI-align, identity order, f4 two-units-per-wave.
// blockIdx%8 = channel group g (pinned to hw XCD). Lanes 0-31 handle unit 2p,
// lanes 32-63 handle unit 2p+1; each half-wave covers the 128-ch slice as
// 32 lanes x float4. Halves VMEM instruction count and per-unit VALU vs f2.
// ---------------------------------------------------------------------------
__global__ __launch_bounds__(256) void roi_align_kernel(
    const float* __restrict__ img,   // [128][128][1024]
    const int*   __restrict__ rois,  // [512][4] = x,y,w,h
    float*       __restrict__ out)   // [512][7][7][1024]
{
    const int g    = blockIdx.x & (NXCD - 1);    // channel group == XCD
    const int wave = threadIdx.x >> 6;
    const int half = (threadIdx.x >> 5) & 1;     // unit within pair
    const int l    = threadIdx.x & 31;           // lane within half-wave
    const int wid  = ((blockIdx.x >> 3) << 2) + wave;  // 0..895 per group

    const float* gimg = img + g * CPG + l * 4;   // fold lane offset in once
    float*       gout = out + g * CPG + l * 4;

#pragma unroll 1
    for (int i = 0; i < 2; ++i) {
        const int p = wid + i * WPG;             // pair id 0..1791
        const int u = 2 * p + half;              // unit 0..3583
        const int r  = u / POOL;
        const int py = u - r * POOL;

        // per-lane ROI fetch (2 distinct per wave -> 2 cache lines)
        const int4 roi = ((const int4*)rois)[r];
        const int rx = roi.x, ry = roi.y, rw = roi.z, rh = roi.w;

        // y axis sample
        const float hf = (float)rh;
        float cy = ((float)py + 0.5f) * (hf / (float)POOL) - 0.5f;
        cy = fminf(fmaxf(cy, 0.0f), fmaxf(hf - 1.0f, 0.0f));
        const int  iy0 = (int)floorf(cy);
        const int  iy1 = min(iy0 + 1, rh - 1);
        const float ty = cy - (float)iy0;

        const int y0 = ry + iy0, y1 = ry + iy1;
        const float* row0 = gimg + (size_t)y0 * HW * CH;
        const float* row1 = gimg + (size_t)y1 * HW * CH;

        const float wf = (float)rw;
        const float xscale = wf / (float)POOL;

        int   x0a[POOL], x1a[POOL];
        float txa[POOL];
#pragma unroll
        for (int px = 0; px < POOL; ++px) {
            float cx = ((float)px + 0.5f) * xscale - 0.5f;
            cx = fminf(fmaxf(cx, 0.0f), fmaxf(wf - 1.0f, 0.0f));
            const int ix0 = (int)floorf(cx);
            const int ix1 = min(ix0 + 1, rw - 1);
            txa[px] = cx - (float)ix0;
            x0a[px] = rx + ix0;
            x1a[px] = rx + ix1;
        }

        float* obase = gout + ((size_t)r * 49 + (size_t)py * POOL) * CH;

        // px loop: 4 f4 loads + blend + 1 f4 nt-store per px; compiler
        // software-pipelines to its VGPR comfort (same bytes, half the instrs)
#pragma unroll
        for (int px = 0; px < POOL; ++px) {
            const f4 v00 = *(const f4*)(row0 + (size_t)x0a[px] * CH);
            const f4 v01 = *(const f4*)(row0 + (size_t)x1a[px] * CH);
            const f4 v10 = *(const f4*)(row1 + (size_t)x0a[px] * CH);
            const f4 v11 = *(const f4*)(row1 + (size_t)x1a[px] * CH);
            const float tx = txa[px];
            f4 top = v00 + tx * (v01 - v00);
            f4 bot = v10 + tx * (v11 - v10);
            f4 res = top + ty * (bot - top);
            __builtin_nontemporal_store(res, (f4*)(obase + (size_t)px * CH));
        }
    }
}

extern "C" void kernel_launch(void* const* d_in, const int* in_sizes, int n_in,
                              void* d_out, int out_size, void* d_ws, size_t ws_size,
                              hipStream_t stream) {
    const float* img  = (const float*)d_in[0];
    const int*   rois = (const int*)d_in[1];
    float*       out  = (float*)d_out;

    roi_align_kernel<<<NBLK_P, 256, 0, stream>>>(img, rois, out);
}